// Round 28
// baseline (50.065 us; speedup 1.0000x reference)
//
#include <hip/hip_runtime.h>
#include <hip/hip_bf16.h>

// out[n,f] = weights[n] * ( x[n,:] . Wsum[f,:] + bsum[f] )
// Wsum = sum_e W[e], bsum = sum_e b[e]  (expert sum commutes with Linear).
// Wsum stored fragment-major ("Bfrag", R6) -> dense lane-consecutive B streams.
// R27: LAST PROBE -- global_load_lds DMA staging (guide Common-mistake #1,
// never cleanly tested). LDS holds the f32 A-tile (128 KB, single 64-token
// tile, R22-proven shape); staged by 16 fire-and-forget DMAs/wave with
// inverse-swizzled per-lane SOURCE + linear dest + swizzled READ (rule #21).
// f32->bf16 conversion moves to the LDS-read side (cvt_pk via
// __float22bfloat162_rn; VALUBusy had 9% headroom). Deletes all staging
// registers and load->cvt->ds_write chains; front = pure issue + barrier with
// 128KB/block in flight. Kloop = champion depth-3 pinned B rotation.

#define N_TOK 32768
#define DIM   512
#define NEXP  8
#define BM    64            // tokens per block (single tile)

typedef __attribute__((ext_vector_type(8))) short  bf16x8;
typedef __attribute__((ext_vector_type(4))) float  f32x4;

__device__ __forceinline__ unsigned int pk2bf(float a, float b) {
    unsigned ua = __float_as_uint(a), ub = __float_as_uint(b);
    ua = (ua + 0x7FFFu + ((ua >> 16) & 1u)) >> 16;   // RNE to bf16
    ub = (ub + 0x7FFFu + ((ub >> 16) & 1u)) >> 16;
    return ua | (ub << 16);
}

__device__ __forceinline__ unsigned int cvt2(float a, float b) {
    __hip_bfloat162 h = __float22bfloat162_rn(make_float2(a, b));   // v_cvt_pk_bf16_f32 (RNE)
    unsigned int r;
    __builtin_memcpy(&r, &h, 4);
    return r;
}

// ---------------- prep: Bfrag (bf16, fragment-major) + bsum (f32) ---- (proven) ----
__global__ __launch_bounds__(64) void moe_prep(const float* __restrict__ W,
                                               const float* __restrict__ b,
                                               unsigned short* __restrict__ Bfrag,
                                               float* __restrict__ bsum) {
    const int g = blockIdx.x * 64 + threadIdx.x;     // 0..32767
    const int f = g >> 6;
    const int q = g & 63;
    const float* src = W + (size_t)f * DIM + q * 8;
    float s0 = 0, s1 = 0, s2 = 0, s3 = 0, s4 = 0, s5 = 0, s6 = 0, s7 = 0;
#pragma unroll
    for (int e = 0; e < NEXP; ++e) {
        float4 u0 = *(const float4*)(src + (size_t)e * DIM * DIM);
        float4 u1 = *(const float4*)(src + (size_t)e * DIM * DIM + 4);
        s0 += u0.x; s1 += u0.y; s2 += u0.z; s3 += u0.w;
        s4 += u1.x; s5 += u1.y; s6 += u1.z; s7 += u1.w;
    }
    uint4 v;
    v.x = pk2bf(s0, s1); v.y = pk2bf(s2, s3);
    v.z = pk2bf(s4, s5); v.w = pk2bf(s6, s7);

    const int F  = f >> 6, j = (f >> 4) & 3, lr = f & 15;
    const int sl = q >> 2, lg = q & 3;
    const int idx16 = ((F * 4 + j) * 16 + sl) * 64 + (lg * 16 + lr);
    *(uint4*)(Bfrag + (size_t)idx16 * 8) = v;

    if (g < DIM / 4) {
        float4 bs = make_float4(0.f, 0.f, 0.f, 0.f);
#pragma unroll
        for (int e = 0; e < NEXP; ++e) {
            float4 u = *(const float4*)(b + e * DIM + g * 4);
            bs.x += u.x; bs.y += u.y; bs.z += u.z; bs.w += u.w;
        }
        *(float4*)(bsum + g * 4) = bs;
    }
}

// ---------------- main GEMM: single 64-token tile, DMA-staged f32 A ----------------
// Grid 512 (1 block/CU resident via 128KB LDS; 2 sequential rounds/CU -- block
// n+1's DMA front overlaps block n's store drain). Wave w owns features
// [w*64,(w+1)*64). LDS layout: row r (0..63) = 2048B; 16B chunk c stored at
// slot c^(r&7) (low-3-bit XOR, involution). DMA writes LINEAR dest; the
// per-lane global SOURCE fetches chunk (c^(r&7)) so linear LDS holds the
// swizzled arrangement; reads apply the same XOR.
__global__ __launch_bounds__(512, 2) void moe_gemm(const float* __restrict__ x,
                                                   const float* __restrict__ wts,
                                                   const unsigned short* __restrict__ Bf,
                                                   const float* __restrict__ bsum,
                                                   float* __restrict__ out) {
    __shared__ __align__(16) unsigned char ldsA[BM * DIM * 4];   // 128 KB (f32 tile)

    const int tid  = threadIdx.x;
    const int lane = tid & 63;
    const int w    = tid >> 6;       // 0..7
    const int lr   = lane & 15;
    const int lg   = lane >> 4;
    const int m0   = blockIdx.x * BM;
    const int f0   = w * 64;

    // ---- front: DMA-stage rows w*8 .. w*8+7 (two 1KB halves per row).
    //      Lane l of half h covers LDS chunk c_lin = h*64+l (linear dest);
    //      its SOURCE is global granule (c_lin & ~7) | ((c_lin ^ row) & 7).
    {
        const int r0 = w * 8;
#pragma unroll
        for (int k = 0; k < 8; ++k) {
            const int row = r0 + k;
            const float* xrow = x + (size_t)(m0 + row) * DIM;
#pragma unroll
            for (int h = 0; h < 2; ++h) {
                const int cl = h * 64 + lane;
                const int g  = (cl & ~7) | ((cl ^ row) & 7);
                __builtin_amdgcn_global_load_lds(
                    (const __attribute__((address_space(1))) void*)(xrow + g * 4),
                    (__attribute__((address_space(3))) void*)(ldsA + row * 2048 + h * 1024),
                    16, 0, 0);
            }
        }
    }
    __syncthreads();                  // the ONLY barrier (drains vmcnt: DMA complete)

    // ---- kloop (champion depth-3 pinned), A read as f32 + cvt_pk at read
    const bf16x8* bfr = (const bf16x8*)Bf + (size_t)w * 4096 + lane;   // + j*1024 + s*64

    f32x4 acc[4][4] = {};
    bf16x8 b0[4], b1[4], b2[4], af[4];

    auto loadB = [&](int s, bf16x8 (&bb)[4]) {
#pragma unroll
        for (int j = 0; j < 4; ++j)
            bb[j] = bfr[j * 1024 + s * 64];
    };
    // slice s covers f32 chunks [s*8, s*8+8) per row; fragment (row, lg) needs
    // chunks s*8+2lg, s*8+2lg+1 -> swizzled slots s*8 + ((2lg)^(r&7)), +((2lg+1)^(r&7)).
    auto sliceA = [&](int s) {
#pragma unroll
        for (int i = 0; i < 4; ++i) {
            const int row = i * 16 + lr;
            const int c0  = s * 8 + (((2 * lg)     ^ row) & 7) + ((2 * lg) & ~7);
            const int c1  = s * 8 + (((2 * lg + 1) ^ row) & 7) + ((2 * lg + 1) & ~7);
            f32x4 lo = *(const f32x4*)(ldsA + row * 2048 + c0 * 16);
            f32x4 hi = *(const f32x4*)(ldsA + row * 2048 + c1 * 16);
            uint4 v;
            v.x = cvt2(lo[0], lo[1]); v.y = cvt2(lo[2], lo[3]);
            v.z = cvt2(hi[0], hi[1]); v.w = cvt2(hi[2], hi[3]);
            __builtin_memcpy(&af[i], &v, 16);
        }
    };
    auto mf = [&](bf16x8 (&bb)[4]) {
#pragma unroll
        for (int j = 0; j < 4; ++j)
#pragma unroll
            for (int i = 0; i < 4; ++i)
                acc[j][i] = __builtin_amdgcn_mfma_f32_16x16x32_bf16(bb[j], af[i], acc[j][i], 0, 0, 0);
    };

    loadB(0, b0); loadB(1, b1); loadB(2, b2);
#define KSTEP(s, BSET)                                        \
    { sliceA(s); mf(BSET);                                    \
      if ((s) + 3 < 16) loadB((s) + 3, BSET);                 \
      __builtin_amdgcn_sched_barrier(0); }
    KSTEP(0,  b0) KSTEP(1,  b1) KSTEP(2,  b2)
    KSTEP(3,  b0) KSTEP(4,  b1) KSTEP(5,  b2)
    KSTEP(6,  b0) KSTEP(7,  b1) KSTEP(8,  b2)
    KSTEP(9,  b0) KSTEP(10, b1) KSTEP(11, b2)
    KSTEP(12, b0) KSTEP(13, b1) KSTEP(14, b2)
    KSTEP(15, b0)
#undef KSTEP

    // ---- epilogue (proven): token = m0 + i*16 + lr; feats = f0 + j*16 + lg*4
    f32x4 bs4[4];
#pragma unroll
    for (int j = 0; j < 4; ++j)
        bs4[j] = *(const f32x4*)(bsum + f0 + j * 16 + lg * 4);
#pragma unroll
    for (int i = 0; i < 4; ++i) {
        const int row = m0 + i * 16 + lr;
        const float wt = wts[row];
#pragma unroll
        for (int j = 0; j < 4; ++j) {
            f32x4 v;
            v[0] = wt * (acc[j][i][0] + bs4[j][0]);
            v[1] = wt * (acc[j][i][1] + bs4[j][1]);
            v[2] = wt * (acc[j][i][2] + bs4[j][2]);
            v[3] = wt * (acc[j][i][3] + bs4[j][3]);
            *(f32x4*)(out + (size_t)row * DIM + f0 + j * 16 + lg * 4) = v;
        }
    }
}

extern "C" void kernel_launch(void* const* d_in, const int* in_sizes, int n_in,
                              void* d_out, int out_size, void* d_ws, size_t ws_size,
                              hipStream_t stream) {
    const float* x   = (const float*)d_in[0];   // [N, D]
    const float* wts = (const float*)d_in[1];   // [N, 1]
    const float* W   = (const float*)d_in[2];   // [E, D, D]
    const float* b   = (const float*)d_in[3];   // [E, D]
    float* out       = (float*)d_out;           // [N, D]

    unsigned short* Bfrag = (unsigned short*)d_ws;                    // 512 KB bf16
    float*          bsum  = (float*)((char*)d_ws + DIM * DIM * 2);    // 2 KB f32

    moe_prep<<<dim3((DIM * DIM / 8) / 64), dim3(64), 0, stream>>>(W, b, Bfrag, bsum);

    moe_gemm<<<dim3(N_TOK / BM), dim3(512), 0, stream>>>(x, wts, Bfrag, bsum, out);
}

// Round 29
// 40.741 us; speedup vs baseline: 1.2288x; 1.2288x over previous
//
#include <hip/hip_runtime.h>
#include <hip/hip_bf16.h>

// FINAL (consolidated champion, ~40.7-41.0us reported; 1.63x over R0's 66.5).
// out[n,f] = weights[n] * ( x[n,:] . Wsum[f,:] + bsum[f] )
// Wsum = sum_e W[e], bsum = sum_e b[e]  (expert sum commutes with Linear).
//
// Proven mechanisms (each isolated across R0-R27):
//  - Algebraic collapse: 8-expert MoE == ONE bf16 GEMM vs Wsum (8x FLOPs/traffic).
//  - Bfrag: Wsum pre-permuted to MFMA-fragment-major in prep -> B-loads are dense
//    lane-consecutive 16B streams from L2 (R6, -12.5us; gathers were the serializer).
//  - Swapped-operand MFMA (mfma(B,A)): lane owns 4 consecutive features of one
//    token -> direct dwordx4 stores, ~1.02x write amplification (R3).
//  - A staged once per tile to XOR-swizzled LDS, bf16 conversion AT STAGE TIME
//    (R27 falsified read-side cvt: 16x VALU multiplier, 2x LDS bytes).
//  - Depth-3 named-set B prefetch, sched_barrier(0)-pinned per slice (R16, -3us).
//  - Tile1 staging folded into kloop(0): loads issue early (steps 0-7), convert+
//    ds_write late (steps 8-15) (R19; == dedicated stager waves, fewer waves).
// Falsified levers (all land 40.6+-1.0 or worse): stager width (R13/R17/R18),
// half-front (R20), 2 blocks/CU (R14/R22), B-prologue hoist (R23: spills),
// bounced tail (R24/R25), streaming decomposition (R15), NT stores (R7),
// bigger tiles (R8/R12), global_load_lds DMA staging (R27).
// Constraint: kloop needs 80-128 VGPR -> 16 waves/CU ceiling; at that occupancy
// no pipe is >35% busy -- latency-bound plateau of this structure under hipcc.

#define N_TOK 32768
#define DIM   512
#define NEXP  8
#define BM    64            // tokens per tile
#define TILES 2             // tiles per block

typedef __attribute__((ext_vector_type(8))) short  bf16x8;
typedef __attribute__((ext_vector_type(4))) float  f32x4;

__device__ __forceinline__ unsigned int pk2bf(float a, float b) {
    unsigned ua = __float_as_uint(a), ub = __float_as_uint(b);
    ua = (ua + 0x7FFFu + ((ua >> 16) & 1u)) >> 16;   // RNE to bf16
    ub = (ub + 0x7FFFu + ((ub >> 16) & 1u)) >> 16;
    return ua | (ub << 16);
}

// ---------------- prep: Bfrag (bf16, fragment-major) + bsum (f32) ----------------
__global__ __launch_bounds__(64) void moe_prep(const float* __restrict__ W,
                                               const float* __restrict__ b,
                                               unsigned short* __restrict__ Bfrag,
                                               float* __restrict__ bsum) {
    const int g = blockIdx.x * 64 + threadIdx.x;     // 0..32767
    const int f = g >> 6;
    const int q = g & 63;
    const float* src = W + (size_t)f * DIM + q * 8;
    float s0 = 0, s1 = 0, s2 = 0, s3 = 0, s4 = 0, s5 = 0, s6 = 0, s7 = 0;
#pragma unroll
    for (int e = 0; e < NEXP; ++e) {
        float4 u0 = *(const float4*)(src + (size_t)e * DIM * DIM);
        float4 u1 = *(const float4*)(src + (size_t)e * DIM * DIM + 4);
        s0 += u0.x; s1 += u0.y; s2 += u0.z; s3 += u0.w;
        s4 += u1.x; s5 += u1.y; s6 += u1.z; s7 += u1.w;
    }
    uint4 v;
    v.x = pk2bf(s0, s1); v.y = pk2bf(s2, s3);
    v.z = pk2bf(s4, s5); v.w = pk2bf(s6, s7);

    const int F  = f >> 6, j = (f >> 4) & 3, lr = f & 15;
    const int sl = q >> 2, lg = q & 3;
    const int idx16 = ((F * 4 + j) * 16 + sl) * 64 + (lg * 16 + lr);
    *(uint4*)(Bfrag + (size_t)idx16 * 8) = v;

    if (g < DIM / 4) {
        float4 bs = make_float4(0.f, 0.f, 0.f, 0.f);
#pragma unroll
        for (int e = 0; e < NEXP; ++e) {
            float4 u = *(const float4*)(b + e * DIM + g * 4);
            bs.x += u.x; bs.y += u.y; bs.z += u.z; bs.w += u.w;
        }
        *(float4*)(bsum + g * 4) = bs;
    }
}

// ---- one granule: 8 f32 -> 16B bf16, XOR-swizzled LDS write (proven pair) ----
__device__ __forceinline__ void stage_granule(const float* __restrict__ srcrow,
                                              unsigned char* __restrict__ dstrow,
                                              int g, int row) {
    float4 u0 = *(const float4*)(srcrow + g * 8);
    float4 u1 = *(const float4*)(srcrow + g * 8 + 4);
    const int sg = (g & ~7) | ((g ^ row) & 7);
    uint4 v;
    v.x = pk2bf(u0.x, u0.y); v.y = pk2bf(u0.z, u0.w);
    v.z = pk2bf(u1.x, u1.y); v.w = pk2bf(u1.z, u1.w);
    *(uint4*)(dstrow + sg * 16) = v;
}

// ---------------- main GEMM: 8 waves, staging folded into kloop0 ----------------
// Grid 256 (1 block/CU via 128KB LDS). Wave w owns features [w*64,(w+1)*64).
__global__ __launch_bounds__(512, 2) void moe_gemm(const float* __restrict__ x,
                                                   const float* __restrict__ wts,
                                                   const unsigned short* __restrict__ Bf,
                                                   const float* __restrict__ bsum,
                                                   float* __restrict__ out) {
    __shared__ __align__(16) unsigned char ldsA[2][BM * DIM * 2];   // 2 x 64 KB

    const int tid  = threadIdx.x;
    const int lane = tid & 63;
    const int w    = tid >> 6;       // 0..7
    const int lr   = lane & 15;
    const int lg   = lane >> 4;
    const int blk  = blockIdx.x;
    const int f0   = w * 64;

    // ---- staging geometry (both tiles): row = tid>>3 (0..63), slot s0 = tid&7,
    //      granules g = s0 + u*8, u = 0..7 (8 granules/thread, 512 thr -> 64x64).
    const int arow = tid >> 3;
    const int as0  = tid & 7;
    unsigned char* dst0 = ldsA[0] + arow * 1024;
    unsigned char* dst1 = ldsA[1] + arow * 1024;

    // ---- front: stage tile0 with all 8 waves
    {
        const float* srcrow = x + (size_t)(blk * TILES * BM + arow) * DIM;
#pragma unroll
        for (int u = 0; u < 8; ++u)
            stage_granule(srcrow, dst0, as0 + u * 8, arow);
    }
    __syncthreads();                  // bar1: buf0 ready

    // ---- compute lambdas (R16-proven)
    const bf16x8* bfr = (const bf16x8*)Bf + (size_t)w * 4096 + lane;   // + j*1024 + s*64

    f32x4 acc[4][4];
    bf16x8 b0[4], b1[4], b2[4], af[4];

    auto loadB = [&](int s, bf16x8 (&bb)[4]) {
#pragma unroll
        for (int j = 0; j < 4; ++j)
            bb[j] = bfr[j * 1024 + s * 64];
    };
    auto sliceA = [&](int buf, int s) {
#pragma unroll
        for (int i = 0; i < 4; ++i) {
            const int row = i * 16 + lr;
            const int gsl = s * 4 + lg;
            const int sw  = (gsl & ~7) | ((gsl ^ row) & 7);
            af[i] = *(const bf16x8*)(ldsA[buf] + row * 1024 + sw * 16);
        }
    };
    auto mf = [&](bf16x8 (&bb)[4]) {
#pragma unroll
        for (int j = 0; j < 4; ++j)
#pragma unroll
            for (int i = 0; i < 4; ++i)
                acc[j][i] = __builtin_amdgcn_mfma_f32_16x16x32_bf16(bb[j], af[i], acc[j][i], 0, 0, 0);
    };
    auto zacc = [&]() {
#pragma unroll
        for (int j = 0; j < 4; ++j)
#pragma unroll
            for (int i = 0; i < 4; ++i)
                acc[j][i] = f32x4{0.f, 0.f, 0.f, 0.f};
    };
    auto epilogue = [&](int tile) {
        const int m0 = (blk * TILES + tile) * BM;
        f32x4 bs4[4];
#pragma unroll
        for (int j = 0; j < 4; ++j)
            bs4[j] = *(const f32x4*)(bsum + f0 + j * 16 + lg * 4);
#pragma unroll
        for (int i = 0; i < 4; ++i) {
            const int row = m0 + i * 16 + lr;
            const float wt = wts[row];
#pragma unroll
            for (int j = 0; j < 4; ++j) {
                f32x4 v;
                v[0] = wt * (acc[j][i][0] + bs4[j][0]);
                v[1] = wt * (acc[j][i][1] + bs4[j][1]);
                v[2] = wt * (acc[j][i][2] + bs4[j][2]);
                v[3] = wt * (acc[j][i][3] + bs4[j][3]);
                *(f32x4*)(out + (size_t)row * DIM + f0 + j * 16 + lg * 4) = v;
            }
        }
    };

    // ---- in-flight tile1 staging registers (static-indexed via macro literals)
    float4 sA[8], sB[8];
    const float* srcrow1 = x + (size_t)((blk * TILES + 1) * BM + arow) * DIM;

    // ================= kloop(0) with folded tile1 staging =================
    zacc();
    loadB(0, b0); loadB(1, b1); loadB(2, b2);
    // KSTEP s: MFMA slice s (B set s%3), reload B s+3, and:
    //   s in [0,8): ISSUE granule-pair load u=s   (fire early, drains under MFMAs)
    //   s in [8,16): convert+ds_write u=s-8       (write late; bar2 fences)
#define STLOAD(u)                                                          \
        { const float* p = srcrow1 + (as0 + (u) * 8) * 8;                  \
          sA[u] = *(const float4*)p; sB[u] = *(const float4*)(p + 4); }
#define STWRITE(u)                                                         \
        { const int g  = as0 + (u) * 8;                                    \
          const int sg = (g & ~7) | ((g ^ arow) & 7);                      \
          uint4 v;                                                         \
          v.x = pk2bf(sA[u].x, sA[u].y); v.y = pk2bf(sA[u].z, sA[u].w);    \
          v.z = pk2bf(sB[u].x, sB[u].y); v.w = pk2bf(sB[u].z, sB[u].w);    \
          *(uint4*)(dst1 + sg * 16) = v; }
#define KSTEP0(s, BSET)                                                    \
        { sliceA(0, s); mf(BSET);                                          \
          if ((s) + 3 < 16) loadB((s) + 3, BSET);                          \
          if ((s) < 8) { STLOAD(s) } else { STWRITE((s) - 8) }             \
          __builtin_amdgcn_sched_barrier(0); }
    KSTEP0(0,  b0) KSTEP0(1,  b1) KSTEP0(2,  b2)
    KSTEP0(3,  b0) KSTEP0(4,  b1) KSTEP0(5,  b2)
    KSTEP0(6,  b0) KSTEP0(7,  b1) KSTEP0(8,  b2)
    KSTEP0(9,  b0) KSTEP0(10, b1) KSTEP0(11, b2)
    KSTEP0(12, b0) KSTEP0(13, b1) KSTEP0(14, b2)
    KSTEP0(15, b0)
#undef KSTEP0
#undef STWRITE
#undef STLOAD
    __syncthreads();                  // bar2: buf1 ready (ds_writes fenced)

    epilogue(0);                      // tile0 stores issue; drain under kloop1

    // ================= kloop(1), plain R16 =================
    zacc();
    loadB(0, b0); loadB(1, b1); loadB(2, b2);
#define KSTEP(s, BSET)                                        \
        { sliceA(1, s); mf(BSET);                             \
          if ((s) + 3 < 16) loadB((s) + 3, BSET);             \
          __builtin_amdgcn_sched_barrier(0); }
    KSTEP(0,  b0) KSTEP(1,  b1) KSTEP(2,  b2)
    KSTEP(3,  b0) KSTEP(4,  b1) KSTEP(5,  b2)
    KSTEP(6,  b0) KSTEP(7,  b1) KSTEP(8,  b2)
    KSTEP(9,  b0) KSTEP(10, b1) KSTEP(11, b2)
    KSTEP(12, b0) KSTEP(13, b1) KSTEP(14, b2)
    KSTEP(15, b0)
#undef KSTEP

    epilogue(1);                      // tail drain
}

extern "C" void kernel_launch(void* const* d_in, const int* in_sizes, int n_in,
                              void* d_out, int out_size, void* d_ws, size_t ws_size,
                              hipStream_t stream) {
    const float* x   = (const float*)d_in[0];   // [N, D]
    const float* wts = (const float*)d_in[1];   // [N, 1]
    const float* W   = (const float*)d_in[2];   // [E, D, D]
    const float* b   = (const float*)d_in[3];   // [E, D]
    float* out       = (float*)d_out;           // [N, D]

    unsigned short* Bfrag = (unsigned short*)d_ws;                    // 512 KB bf16
    float*          bsum  = (float*)((char*)d_ws + DIM * DIM * 2);    // 2 KB f32

    moe_prep<<<dim3((DIM * DIM / 8) / 64), dim3(64), 0, stream>>>(W, b, Bfrag, bsum);

    moe_gemm<<<dim3(N_TOK / (BM * TILES)), dim3(512), 0, stream>>>(x, wts, Bfrag, bsum, out);
}